// Round 1
// baseline (10764.233 us; speedup 1.0000x reference)
//
#include <hip/hip_runtime.h>
#include <cmath>

#define B_ 4
#define T_ 40
#define N_ 5000
#define F_ 90
#define C_ 256
#define E_ 160000
#define M_TOT (B_*N_)   // 20000

// ---------------- init ----------------
__global__ void init_kernel(int* __restrict__ cnt, float* __restrict__ H, float* __restrict__ Hacc){
    int i = blockIdx.x*blockDim.x + threadIdx.x;
    if (i < N_) cnt[i] = 0;
    const int tot = M_TOT*C_;
    for (int j = i; j < tot; j += gridDim.x*blockDim.x){ H[j] = 0.f; Hacc[j] = 0.f; }
}

// ---------------- degree count ----------------
__global__ void count_kernel(const int* __restrict__ ei, int* __restrict__ cnt){
    int e = blockIdx.x*blockDim.x + threadIdx.x;
    if (e < E_) atomicAdd(&cnt[ei[E_ + e]], 1);
}

// ---------------- dis = deg^-0.5, selfw = dis^2 ----------------
__global__ void dis_kernel(const int* __restrict__ cnt, float* __restrict__ dis, float* __restrict__ selfw){
    int n = blockIdx.x*blockDim.x + threadIdx.x;
    if (n < N_){
        float d = (float)cnt[n] + 1.0f;   // +1 self loop
        float r = 1.0f / sqrtf(d);
        dis[n] = r;
        selfw[n] = r*r;
    }
}

// ---------------- exclusive scan over cnt -> rowptr, pos ----------------
__global__ __launch_bounds__(256) void scan_kernel(const int* __restrict__ cnt, int* __restrict__ rowptr, int* __restrict__ pos){
    const int tid = threadIdx.x;
    const int base = tid*20;
    int v[20]; int s = 0;
    #pragma unroll
    for (int j = 0; j < 20; ++j){
        int idx = base + j;
        int c = (idx < N_) ? cnt[idx] : 0;
        v[j] = s; s += c;
    }
    __shared__ int sh[256];
    sh[tid] = s; __syncthreads();
    for (int off = 1; off < 256; off <<= 1){
        int x = (tid >= off) ? sh[tid-off] : 0;
        __syncthreads();
        sh[tid] += x;
        __syncthreads();
    }
    int excl = sh[tid] - s;
    #pragma unroll
    for (int j = 0; j < 20; ++j){
        int idx = base + j;
        if (idx < N_){ int val = excl + v[j]; rowptr[idx] = val; pos[idx] = val; }
    }
    if (tid == 255) rowptr[N_] = sh[255];
}

// ---------------- CSR scatter ----------------
__global__ void scatter_kernel(const int* __restrict__ ei, const float* __restrict__ dis,
                               int* __restrict__ pos, int* __restrict__ csr_src, float* __restrict__ csr_w){
    int e = blockIdx.x*blockDim.x + threadIdx.x;
    if (e < E_){
        int r = ei[e];
        int c = ei[E_ + e];
        int p = atomicAdd(&pos[c], 1);
        csr_src[p] = r;
        csr_w[p]   = dis[r]*dis[c];
    }
}

// ---------------- softmax over attention (T=40) ----------------
__global__ void softmax_kernel(const float* __restrict__ att, float* __restrict__ probs){
    int t = threadIdx.x;
    float v = (t < T_) ? att[t] : -3.4e38f;
    float m = v;
    for (int o = 32; o > 0; o >>= 1) m = fmaxf(m, __shfl_xor(m, o));
    float e = (t < T_) ? expf(v - m) : 0.f;
    float s = e;
    for (int o = 32; o > 0; o >>= 1) s += __shfl_xor(s, o);
    if (t < T_) probs[t] = e / s;
}

// ---------------- fold weights: Wp[f][g*256+c] = sum_k Wg[f][k]*Lg[k][c] ----------------
__global__ __launch_bounds__(256) void foldw_kernel(const float* __restrict__ Wz, const float* __restrict__ Wr, const float* __restrict__ Wh,
                             const float* __restrict__ Lz, const float* __restrict__ Lr, const float* __restrict__ Lh,
                             float* __restrict__ Wp){
    int g = blockIdx.x / F_;
    int f = blockIdx.x % F_;
    int c = threadIdx.x;
    const float* W = (g == 0) ? Wz : (g == 1) ? Wr : Wh;
    const float* L = (g == 0) ? Lz : (g == 1) ? Lr : Lh;
    float acc = 0.f;
    for (int k = 0; k < C_; ++k) acc += W[f*C_ + k] * L[k*C_ + c];
    Wp[f*768 + g*256 + c] = acc;
}

__global__ __launch_bounds__(256) void foldb_kernel(const float* __restrict__ bz, const float* __restrict__ br, const float* __restrict__ bh,
                             const float* __restrict__ Lz, const float* __restrict__ Lr, const float* __restrict__ Lh,
                             const float* __restrict__ Lzb, const float* __restrict__ Lrb, const float* __restrict__ Lhb,
                             float* __restrict__ bp){
    int g = blockIdx.x;
    int c = threadIdx.x;
    const float* b = (g == 0) ? bz : (g == 1) ? br : bh;
    const float* L = (g == 0) ? Lz : (g == 1) ? Lr : Lh;
    const float* lb = (g == 0) ? Lzb : (g == 1) ? Lrb : Lhb;
    float acc = lb[c];
    for (int k = 0; k < C_; ++k) acc += b[k] * L[k*C_ + c];
    bp[g*256 + c] = acc;
}

// ---------------- SpMM: AXt[b][n][f] = selfw[n]*X[b][t][n][f] + sum_j w_j * X[b][t][src_j][f] ----------------
__global__ __launch_bounds__(256) void spmm_kernel(const float* __restrict__ X, const int* __restrict__ rowptr,
                            const int* __restrict__ csr_src, const float* __restrict__ csr_w,
                            const float* __restrict__ selfw, float* __restrict__ AXt, int t){
    const int n = blockIdx.x;
    const int tid = threadIdx.x;
    __shared__ int   s_src[256];
    __shared__ float s_w[256];
    const int beg = rowptr[n], end = rowptr[n+1];
    const int i0 = tid, i1 = tid + 256;
    const int b0 = i0 / F_, f0 = i0 - b0*F_;
    const int b1 = i1 / F_, f1 = i1 - b1*F_;
    const bool has1 = (i1 < B_*F_);
    const float sw = selfw[n];
    float acc0 = sw * X[((b0*T_ + t)*N_ + n)*F_ + f0];
    float acc1 = has1 ? sw * X[((b1*T_ + t)*N_ + n)*F_ + f1] : 0.f;
    for (int base = beg; base < end; base += 256){
        int cc = min(256, end - base);
        __syncthreads();
        if (tid < cc){ s_src[tid] = csr_src[base + tid]; s_w[tid] = csr_w[base + tid]; }
        __syncthreads();
        for (int j = 0; j < cc; ++j){
            int src = s_src[j]; float w = s_w[j];
            acc0 += w * X[((b0*T_ + t)*N_ + src)*F_ + f0];
            if (has1) acc1 += w * X[((b1*T_ + t)*N_ + src)*F_ + f1];
        }
    }
    AXt[(b0*N_ + n)*F_ + f0] = acc0;
    if (has1) AXt[(b1*N_ + n)*F_ + f1] = acc1;
}

// ---------------- fused GRU GEMM ----------------
// PHASE 0: out cols 0..511 (z|r gates), epilogue: Z, HR = H*sigmoid(r)
// PHASE 1: out cols 0..255 (h gate),   epilogue: H = Z*H + (1-Z)*tanh, Hacc += p_t*H
template<int PHASE>
__global__ __launch_bounds__(256) void gru_gemm(
    const float* __restrict__ Ax,    // [M_TOT][F_]
    const float* __restrict__ Hm,    // [M_TOT][C_]  (H for zr, HR for h)
    const float* __restrict__ Wp,    // [F_][768]
    const float* __restrict__ bp,    // [768]
    const float* __restrict__ Lz, const float* __restrict__ Lr, const float* __restrict__ Lh,
    float* __restrict__ Zb, float* __restrict__ HRb,
    const float* __restrict__ Zin, float* __restrict__ Hio, float* __restrict__ Hacc,
    const float* __restrict__ probs, int t)
{
    __shared__ __align__(16) float As[16][68];   // [kk][row]
    __shared__ __align__(16) float Bs[16][68];   // [kk][col]
    const int tid = threadIdx.x;
    const int tx = tid & 15, ty = tid >> 4;
    const int row0 = blockIdx.x * 64;
    const int col0 = blockIdx.y * 64;

    float acc[4][4] = {};

    const float* B2; int c2ofs;
    if (PHASE == 0){
        if (col0 < 256){ B2 = Lz + 256*C_; c2ofs = col0; }
        else           { B2 = Lr + 256*C_; c2ofs = col0 - 256; }
    } else             { B2 = Lh + 256*C_; c2ofs = col0; }
    const int wcol0 = (PHASE == 0 ? 0 : 512) + col0;

    // ---- segment 1: K = 90 over Ax & Wp ----
    for (int k0 = 0; k0 < F_; k0 += 16){
        __syncthreads();
        for (int l = tid; l < 64*16; l += 256){
            int kk = l & 15, r = l >> 4;
            int gm = row0 + r, gk = k0 + kk;
            As[kk][r] = (gm < M_TOT && gk < F_) ? Ax[gm*F_ + gk] : 0.f;
        }
        for (int l = tid; l < 16*64; l += 256){
            int c = l & 63, kk = l >> 6;
            int gk = k0 + kk;
            Bs[kk][c] = (gk < F_) ? Wp[gk*768 + wcol0 + c] : 0.f;
        }
        __syncthreads();
        #pragma unroll
        for (int kk = 0; kk < 16; ++kk){
            const float4 av = *reinterpret_cast<const float4*>(&As[kk][ty*4]);
            const float4 bv = *reinterpret_cast<const float4*>(&Bs[kk][tx*4]);
            const float aa[4] = {av.x, av.y, av.z, av.w};
            const float bb[4] = {bv.x, bv.y, bv.z, bv.w};
            #pragma unroll
            for (int i = 0; i < 4; ++i)
                #pragma unroll
                for (int j = 0; j < 4; ++j)
                    acc[i][j] = fmaf(aa[i], bb[j], acc[i][j]);
        }
    }
    // ---- segment 2: K = 256 over Hm & L-bottom ----
    for (int k0 = 0; k0 < C_; k0 += 16){
        __syncthreads();
        for (int l = tid; l < 64*16; l += 256){
            int kk = l & 15, r = l >> 4;
            int gm = row0 + r;
            As[kk][r] = (gm < M_TOT) ? Hm[(size_t)gm*C_ + k0 + kk] : 0.f;
        }
        for (int l = tid; l < 16*64; l += 256){
            int c = l & 63, kk = l >> 6;
            Bs[kk][c] = B2[(k0 + kk)*C_ + c2ofs + c];
        }
        __syncthreads();
        #pragma unroll
        for (int kk = 0; kk < 16; ++kk){
            const float4 av = *reinterpret_cast<const float4*>(&As[kk][ty*4]);
            const float4 bv = *reinterpret_cast<const float4*>(&Bs[kk][tx*4]);
            const float aa[4] = {av.x, av.y, av.z, av.w};
            const float bb[4] = {bv.x, bv.y, bv.z, bv.w};
            #pragma unroll
            for (int i = 0; i < 4; ++i)
                #pragma unroll
                for (int j = 0; j < 4; ++j)
                    acc[i][j] = fmaf(aa[i], bb[j], acc[i][j]);
        }
    }

    // ---- epilogue ----
    const float4 bias = *reinterpret_cast<const float4*>(&bp[wcol0 + tx*4]);
    const float bb2[4] = {bias.x, bias.y, bias.z, bias.w};

    if (PHASE == 0){
        const bool zside = (col0 < 256);
        #pragma unroll
        for (int i = 0; i < 4; ++i){
            int m = row0 + ty*4 + i;
            if (m >= M_TOT) continue;
            float4 s4;
            s4.x = 1.f/(1.f + __expf(-(acc[i][0] + bb2[0])));
            s4.y = 1.f/(1.f + __expf(-(acc[i][1] + bb2[1])));
            s4.z = 1.f/(1.f + __expf(-(acc[i][2] + bb2[2])));
            s4.w = 1.f/(1.f + __expf(-(acc[i][3] + bb2[3])));
            if (zside){
                *reinterpret_cast<float4*>(&Zb[(size_t)m*C_ + col0 + tx*4]) = s4;
            } else {
                size_t o = (size_t)m*C_ + c2ofs + tx*4;
                float4 h4 = *reinterpret_cast<const float4*>(&Hm[o]);
                float4 hr;
                hr.x = h4.x*s4.x; hr.y = h4.y*s4.y; hr.z = h4.z*s4.z; hr.w = h4.w*s4.w;
                *reinterpret_cast<float4*>(&HRb[o]) = hr;
            }
        }
    } else {
        const float pt = probs[t];
        #pragma unroll
        for (int i = 0; i < 4; ++i){
            int m = row0 + ty*4 + i;
            if (m >= M_TOT) continue;
            float vx = acc[i][0] + bb2[0];
            float vy = acc[i][1] + bb2[1];
            float vz = acc[i][2] + bb2[2];
            float vw = acc[i][3] + bb2[3];
            // tanh via exp
            float4 ht;
            ht.x = 1.f - 2.f/(__expf(2.f*vx) + 1.f);
            ht.y = 1.f - 2.f/(__expf(2.f*vy) + 1.f);
            ht.z = 1.f - 2.f/(__expf(2.f*vz) + 1.f);
            ht.w = 1.f - 2.f/(__expf(2.f*vw) + 1.f);
            size_t o = (size_t)m*C_ + col0 + tx*4;
            float4 z4 = *reinterpret_cast<const float4*>(&Zin[o]);
            float4 h4 = *reinterpret_cast<const float4*>(&Hio[o]);
            float4 hn;
            hn.x = z4.x*h4.x + (1.f - z4.x)*ht.x;
            hn.y = z4.y*h4.y + (1.f - z4.y)*ht.y;
            hn.z = z4.z*h4.z + (1.f - z4.z)*ht.z;
            hn.w = z4.w*h4.w + (1.f - z4.w)*ht.w;
            *reinterpret_cast<float4*>(&Hio[o]) = hn;
            float4 ha = *reinterpret_cast<const float4*>(&Hacc[o]);
            ha.x += pt*hn.x; ha.y += pt*hn.y; ha.z += pt*hn.z; ha.w += pt*hn.w;
            *reinterpret_cast<float4*>(&Hacc[o]) = ha;
        }
    }
}

// ---------------- final MLP ----------------
__global__ __launch_bounds__(256) void mlp_kernel(const float* __restrict__ Hacc, const int* __restrict__ fids,
                           const float* __restrict__ M1, const float* __restrict__ M1b,
                           const float* __restrict__ M2, const float* __restrict__ M2b,
                           const float* __restrict__ M3, const float* __restrict__ M3b,
                           float* __restrict__ out){
    const int b = blockIdx.x;
    const int tid = threadIdx.x;
    __shared__ float sh[C_];
    __shared__ float s1[64];
    __shared__ float s2[32];
    const int f = fids[b];
    sh[tid] = Hacc[((size_t)(b*N_ + f))*C_ + tid];
    __syncthreads();
    if (tid < 64){
        float a = M1b[tid];
        for (int k = 0; k < C_; ++k) a += sh[k]*M1[k*64 + tid];
        s1[tid] = (a > 0.f) ? a : 0.01f*a;
    }
    __syncthreads();
    if (tid < 32){
        float a = M2b[tid];
        for (int k = 0; k < 64; ++k) a += s1[k]*M2[k*32 + tid];
        s2[tid] = (a > 0.f) ? a : 0.01f*a;
    }
    __syncthreads();
    if (tid < 5){
        float a = M3b[tid];
        for (int k = 0; k < 32; ++k) a += s2[k]*M3[k*5 + tid];
        out[b*5 + tid] = 4.f/(1.f + expf(-a)) + 1.f;
    }
}

extern "C" void kernel_launch(void* const* d_in, const int* in_sizes, int n_in,
                              void* d_out, int out_size, void* d_ws, size_t ws_size,
                              hipStream_t stream) {
    const float* x   = (const float*)d_in[0];
    const int*   ei  = (const int*)d_in[1];
    const int*   fid = (const int*)d_in[2];
    const float* att = (const float*)d_in[3];
    const float* Wz  = (const float*)d_in[4];  const float* bz  = (const float*)d_in[5];
    const float* Wr  = (const float*)d_in[6];  const float* br  = (const float*)d_in[7];
    const float* Wh  = (const float*)d_in[8];  const float* bh  = (const float*)d_in[9];
    const float* Lz  = (const float*)d_in[10]; const float* Lzb = (const float*)d_in[11];
    const float* Lr  = (const float*)d_in[12]; const float* Lrb = (const float*)d_in[13];
    const float* Lh  = (const float*)d_in[14]; const float* Lhb = (const float*)d_in[15];
    const float* M1  = (const float*)d_in[16]; const float* M1b = (const float*)d_in[17];
    const float* M2  = (const float*)d_in[18]; const float* M2b = (const float*)d_in[19];
    const float* M3  = (const float*)d_in[20]; const float* M3b = (const float*)d_in[21];
    float* out = (float*)d_out;

    char* w = (char*)d_ws;
    auto alloc = [&](size_t bytes)->void*{ void* p = (void*)w; w += ((bytes + 255)/256)*256; return p; };
    int*   cnt     = (int*)  alloc((size_t)N_*4);
    int*   rowptr  = (int*)  alloc((size_t)(N_+1)*4);
    int*   pos     = (int*)  alloc((size_t)N_*4);
    float* dis     = (float*)alloc((size_t)N_*4);
    float* selfw   = (float*)alloc((size_t)N_*4);
    int*   csr_src = (int*)  alloc((size_t)E_*4);
    float* csr_w   = (float*)alloc((size_t)E_*4);
    float* probs   = (float*)alloc((size_t)T_*4);
    float* Wp      = (float*)alloc((size_t)F_*768*4);
    float* bp      = (float*)alloc((size_t)768*4);
    float* AXt     = (float*)alloc((size_t)B_*N_*F_*4);
    float* H       = (float*)alloc((size_t)M_TOT*C_*4);
    float* HR      = (float*)alloc((size_t)M_TOT*C_*4);
    float* Zb      = (float*)alloc((size_t)M_TOT*C_*4);
    float* Hacc    = (float*)alloc((size_t)M_TOT*C_*4);

    init_kernel<<<2048, 256, 0, stream>>>(cnt, H, Hacc);
    count_kernel<<<(E_ + 255)/256, 256, 0, stream>>>(ei, cnt);
    dis_kernel<<<(N_ + 255)/256, 256, 0, stream>>>(cnt, dis, selfw);
    scan_kernel<<<1, 256, 0, stream>>>(cnt, rowptr, pos);
    scatter_kernel<<<(E_ + 255)/256, 256, 0, stream>>>(ei, dis, pos, csr_src, csr_w);
    softmax_kernel<<<1, 64, 0, stream>>>(att, probs);
    foldw_kernel<<<3*F_, 256, 0, stream>>>(Wz, Wr, Wh, Lz, Lr, Lh, Wp);
    foldb_kernel<<<3, 256, 0, stream>>>(bz, br, bh, Lz, Lr, Lh, Lzb, Lrb, Lhb, bp);

    const dim3 gemm_blk(256);
    const dim3 gridA((M_TOT + 63)/64, 8);   // 512 cols
    const dim3 gridC((M_TOT + 63)/64, 4);   // 256 cols

    for (int t = 0; t < T_; ++t){
        spmm_kernel<<<N_, 256, 0, stream>>>(x, rowptr, csr_src, csr_w, selfw, AXt, t);
        gru_gemm<0><<<gridA, gemm_blk, 0, stream>>>(AXt, H, Wp, bp, Lz, Lr, Lh,
                                                    Zb, HR, nullptr, nullptr, nullptr, probs, t);
        gru_gemm<1><<<gridC, gemm_blk, 0, stream>>>(AXt, HR, Wp, bp, Lz, Lr, Lh,
                                                    nullptr, nullptr, Zb, H, Hacc, probs, t);
    }
    mlp_kernel<<<B_, 256, 0, stream>>>(Hacc, fid, M1, M1b, M2, M2b, M3, M3b, out);
}

// Round 2
// 4709.935 us; speedup vs baseline: 2.2854x; 2.2854x over previous
//
#include <hip/hip_runtime.h>
#include <hip/hip_bf16.h>
#include <cmath>

#define B_ 4
#define T_ 40
#define N_ 5000
#define F_ 90
#define C_ 256
#define E_ 160000
#define M_TOT (B_*N_)   // 20000
#define M_PAD 20032     // 313*64
#define KP_ 96          // padded F (multiple of 32)
#define NKT 11          // (96+256)/32
#define NCT 48          // 768/16

typedef __attribute__((ext_vector_type(8))) short s16x8;
typedef __attribute__((ext_vector_type(4))) float f32x4;

// ---------------- init ----------------
__global__ void init_kernel(int* __restrict__ cnt, float* __restrict__ H, float* __restrict__ Hacc,
                            unsigned* __restrict__ HbU, unsigned* __restrict__ AxpU, unsigned* __restrict__ HRbU){
    const int i = blockIdx.x*blockDim.x + threadIdx.x;
    const int stride = gridDim.x*blockDim.x;
    for (int j = i; j < N_; j += stride) cnt[j] = 0;
    for (int j = i; j < M_PAD*C_; j += stride) H[j] = 0.f;
    for (int j = i; j < M_TOT*C_; j += stride) Hacc[j] = 0.f;
    for (int j = i; j < M_PAD*C_/2; j += stride) HbU[j] = 0u;   // bf16 zeros
    const int padAxp = (M_PAD - M_TOT)*KP_/2;
    for (int j = i; j < padAxp; j += stride) AxpU[M_TOT*KP_/2 + j] = 0u;
    const int padHRb = (M_PAD - M_TOT)*C_/2;
    for (int j = i; j < padHRb; j += stride) HRbU[M_TOT*C_/2 + j] = 0u;
}

// ---------------- degree count ----------------
__global__ void count_kernel(const int* __restrict__ ei, int* __restrict__ cnt){
    int e = blockIdx.x*blockDim.x + threadIdx.x;
    if (e < E_) atomicAdd(&cnt[ei[E_ + e]], 1);
}

// ---------------- dis = deg^-0.5, selfw = dis^2 ----------------
__global__ void dis_kernel(const int* __restrict__ cnt, float* __restrict__ dis, float* __restrict__ selfw){
    int n = blockIdx.x*blockDim.x + threadIdx.x;
    if (n < N_){
        float d = (float)cnt[n] + 1.0f;   // +1 self loop
        float r = 1.0f / sqrtf(d);
        dis[n] = r;
        selfw[n] = r*r;
    }
}

// ---------------- exclusive scan over cnt -> rowptr, pos ----------------
__global__ __launch_bounds__(256) void scan_kernel(const int* __restrict__ cnt, int* __restrict__ rowptr, int* __restrict__ pos){
    const int tid = threadIdx.x;
    const int base = tid*20;
    int v[20]; int s = 0;
    #pragma unroll
    for (int j = 0; j < 20; ++j){
        int idx = base + j;
        int c = (idx < N_) ? cnt[idx] : 0;
        v[j] = s; s += c;
    }
    __shared__ int sh[256];
    sh[tid] = s; __syncthreads();
    for (int off = 1; off < 256; off <<= 1){
        int x = (tid >= off) ? sh[tid-off] : 0;
        __syncthreads();
        sh[tid] += x;
        __syncthreads();
    }
    int excl = sh[tid] - s;
    #pragma unroll
    for (int j = 0; j < 20; ++j){
        int idx = base + j;
        if (idx < N_){ int val = excl + v[j]; rowptr[idx] = val; pos[idx] = val; }
    }
    if (tid == 255) rowptr[N_] = sh[255];
}

// ---------------- CSR scatter ----------------
__global__ void scatter_kernel(const int* __restrict__ ei, const float* __restrict__ dis,
                               int* __restrict__ pos, int* __restrict__ csr_src, float* __restrict__ csr_w){
    int e = blockIdx.x*blockDim.x + threadIdx.x;
    if (e < E_){
        int r = ei[e];
        int c = ei[E_ + e];
        int p = atomicAdd(&pos[c], 1);
        csr_src[p] = r;
        csr_w[p]   = dis[r]*dis[c];
    }
}

// ---------------- softmax over attention (T=40) ----------------
__global__ void softmax_kernel(const float* __restrict__ att, float* __restrict__ probs){
    int t = threadIdx.x;
    float v = (t < T_) ? att[t] : -3.4e38f;
    float m = v;
    for (int o = 32; o > 0; o >>= 1) m = fmaxf(m, __shfl_xor(m, o));
    float e = (t < T_) ? expf(v - m) : 0.f;
    float s = e;
    for (int o = 32; o > 0; o >>= 1) s += __shfl_xor(s, o);
    if (t < T_) probs[t] = e / s;
}

// ---------------- fold weights: Wp[f][g*256+c] = sum_k Wg[f][k]*Lg[k][c] ----------------
__global__ __launch_bounds__(256) void foldw_kernel(const float* __restrict__ Wz, const float* __restrict__ Wr, const float* __restrict__ Wh,
                             const float* __restrict__ Lz, const float* __restrict__ Lr, const float* __restrict__ Lh,
                             float* __restrict__ Wp){
    int g = blockIdx.x / F_;
    int f = blockIdx.x % F_;
    int c = threadIdx.x;
    const float* W = (g == 0) ? Wz : (g == 1) ? Wr : Wh;
    const float* L = (g == 0) ? Lz : (g == 1) ? Lr : Lh;
    float acc = 0.f;
    for (int k = 0; k < C_; ++k) acc += W[f*C_ + k] * L[k*C_ + c];
    Wp[f*768 + g*256 + c] = acc;
}

__global__ __launch_bounds__(256) void foldb_kernel(const float* __restrict__ bz, const float* __restrict__ br, const float* __restrict__ bh,
                             const float* __restrict__ Lz, const float* __restrict__ Lr, const float* __restrict__ Lh,
                             const float* __restrict__ Lzb, const float* __restrict__ Lrb, const float* __restrict__ Lhb,
                             float* __restrict__ bp){
    int g = blockIdx.x;
    int c = threadIdx.x;
    const float* b = (g == 0) ? bz : (g == 1) ? br : bh;
    const float* L = (g == 0) ? Lz : (g == 1) ? Lr : Lh;
    const float* lb = (g == 0) ? Lzb : (g == 1) ? Lrb : Lhb;
    float acc = lb[c];
    for (int k = 0; k < C_; ++k) acc += b[k] * L[k*C_ + c];
    bp[g*256 + c] = acc;
}

// ---------------- pack folded weight [352][768] into MFMA B-fragment order ----------------
// Bp[((kt*NCT + ct)*64 + lane)*8 + j] = W[kt*32 + (lane>>4)*8 + j][ct*16 + (lane&15)]
// rows 0..89 = Wp, 90..95 = 0, 96..351 = L_{z|r|h}[256 + (k-96)][c%256] per column group
__global__ __launch_bounds__(256) void pack_kernel(const float* __restrict__ Wp,
                             const float* __restrict__ Lz, const float* __restrict__ Lr, const float* __restrict__ Lh,
                             __hip_bfloat16* __restrict__ Bp){
    const int kt = blockIdx.x / NCT;
    const int ct = blockIdx.x % NCT;
    const int tid = threadIdx.x;
    const int l = tid & 63;
    const int jp = tid >> 6;           // 0..3, each thread does j = jp*2, jp*2+1
    const int c = ct*16 + (l & 15);
    #pragma unroll
    for (int jj = 0; jj < 2; ++jj){
        const int j = jp*2 + jj;
        const int k = kt*32 + (l >> 4)*8 + j;
        float v;
        if (k < F_) v = Wp[k*768 + c];
        else if (k < KP_) v = 0.f;
        else {
            int kk = k - KP_;
            int g = c >> 8, c2 = c & 255;
            const float* L = (g == 0) ? Lz : (g == 1) ? Lr : Lh;
            v = L[(256 + kk)*C_ + c2];
        }
        Bp[((size_t)(kt*NCT + ct)*64 + l)*8 + j] = __float2bfloat16(v);
    }
}

// ---------------- SpMM: Axp[b*N+n][f] = selfw[n]*X[b][t][n][f] + sum_j w_j * X[b][t][src_j][f]  (bf16 out, padded to 96) ----------------
__global__ __launch_bounds__(256) void spmm_kernel(const float* __restrict__ X, const int* __restrict__ rowptr,
                            const int* __restrict__ csr_src, const float* __restrict__ csr_w,
                            const float* __restrict__ selfw, __hip_bfloat16* __restrict__ Axp, int t){
    const int n = blockIdx.x;
    const int tid = threadIdx.x;
    __shared__ int   s_src[256];
    __shared__ float s_w[256];
    const int beg = rowptr[n], end = rowptr[n+1];
    const int i0 = tid, i1 = tid + 256;
    const int b0 = i0 / F_, f0 = i0 - b0*F_;
    const int b1 = i1 / F_, f1 = i1 - b1*F_;
    const bool has1 = (i1 < B_*F_);
    const float sw = selfw[n];
    float acc0 = sw * X[((b0*T_ + t)*N_ + n)*F_ + f0];
    float acc1 = has1 ? sw * X[((b1*T_ + t)*N_ + n)*F_ + f1] : 0.f;
    for (int base = beg; base < end; base += 256){
        int cc = min(256, end - base);
        __syncthreads();
        if (tid < cc){ s_src[tid] = csr_src[base + tid]; s_w[tid] = csr_w[base + tid]; }
        __syncthreads();
        for (int j = 0; j < cc; ++j){
            int src = s_src[j]; float w = s_w[j];
            acc0 += w * X[((b0*T_ + t)*N_ + src)*F_ + f0];
            if (has1) acc1 += w * X[((b1*T_ + t)*N_ + src)*F_ + f1];
        }
    }
    Axp[(size_t)(b0*N_ + n)*KP_ + f0] = __float2bfloat16(acc0);
    if (has1) Axp[(size_t)(b1*N_ + n)*KP_ + f1] = __float2bfloat16(acc1);
    if (tid < B_*(KP_ - F_)){
        int b = tid / (KP_ - F_), f = F_ + tid % (KP_ - F_);
        Axp[(size_t)(b*N_ + n)*KP_ + f] = __float2bfloat16(0.f);
    }
}

// ---------------- fused GRU GEMM via MFMA (no LDS; direct global loads, L2-resident B) ----------------
// PHASE 0: cols 0..511 (z|r). epilogue: Zb = sigmoid, HRb(bf16) = H*sigmoid(r)
// PHASE 1: cols 512..767 (h). epilogue: H = Z*H + (1-Z)*tanh; Hb = bf16(H); Hacc += p_t*H
template<int PHASE>
__global__ __launch_bounds__(256) void gemm_mfma(
    const s16x8* __restrict__ Axp,   // [M_PAD][12]  (96 bf16 / row)
    const s16x8* __restrict__ Hm,    // [M_PAD][32]  (256 bf16 / row): Hb (P0) or HRb (P1)
    const s16x8* __restrict__ Bp,    // [11*48*64] fragments
    const float* __restrict__ bp,    // [768]
    float* __restrict__ H,           // fp32 state: read (P0), read+write (P1)
    float* __restrict__ Zb,
    __hip_bfloat16* __restrict__ HRb,
    __hip_bfloat16* __restrict__ Hb,
    float* __restrict__ Hacc,
    const float* __restrict__ probs, int t)
{
    const int tid = threadIdx.x;
    const int l = tid & 63, w = tid >> 6;
    const int wr = w >> 1, wc = w & 1;
    const int row0 = blockIdx.x*64 + wr*32;
    const int colbase = (PHASE == 0 ? 0 : 512) + blockIdx.y*128 + wc*64;
    const int lr = l & 15, lk = l >> 4;
    const int ct0 = colbase >> 4;

    f32x4 acc[2][4] = {};

    const int ar0 = row0 + lr;
    const int ar1 = row0 + 16 + lr;

    // ---- K-segment 1: Axp (96) ----
    #pragma unroll
    for (int kt = 0; kt < 3; ++kt){
        s16x8 a0 = Axp[(size_t)ar0*12 + kt*4 + lk];
        s16x8 a1 = Axp[(size_t)ar1*12 + kt*4 + lk];
        s16x8 b0 = Bp[((size_t)(kt*NCT + ct0 + 0) << 6) + l];
        s16x8 b1 = Bp[((size_t)(kt*NCT + ct0 + 1) << 6) + l];
        s16x8 b2 = Bp[((size_t)(kt*NCT + ct0 + 2) << 6) + l];
        s16x8 b3 = Bp[((size_t)(kt*NCT + ct0 + 3) << 6) + l];
        acc[0][0] = __builtin_amdgcn_mfma_f32_16x16x32_bf16(a0, b0, acc[0][0], 0, 0, 0);
        acc[0][1] = __builtin_amdgcn_mfma_f32_16x16x32_bf16(a0, b1, acc[0][1], 0, 0, 0);
        acc[0][2] = __builtin_amdgcn_mfma_f32_16x16x32_bf16(a0, b2, acc[0][2], 0, 0, 0);
        acc[0][3] = __builtin_amdgcn_mfma_f32_16x16x32_bf16(a0, b3, acc[0][3], 0, 0, 0);
        acc[1][0] = __builtin_amdgcn_mfma_f32_16x16x32_bf16(a1, b0, acc[1][0], 0, 0, 0);
        acc[1][1] = __builtin_amdgcn_mfma_f32_16x16x32_bf16(a1, b1, acc[1][1], 0, 0, 0);
        acc[1][2] = __builtin_amdgcn_mfma_f32_16x16x32_bf16(a1, b2, acc[1][2], 0, 0, 0);
        acc[1][3] = __builtin_amdgcn_mfma_f32_16x16x32_bf16(a1, b3, acc[1][3], 0, 0, 0);
    }
    // ---- K-segment 2: Hm (256) ----
    #pragma unroll
    for (int kt = 0; kt < 8; ++kt){
        s16x8 a0 = Hm[(size_t)ar0*32 + kt*4 + lk];
        s16x8 a1 = Hm[(size_t)ar1*32 + kt*4 + lk];
        s16x8 b0 = Bp[((size_t)((kt+3)*NCT + ct0 + 0) << 6) + l];
        s16x8 b1 = Bp[((size_t)((kt+3)*NCT + ct0 + 1) << 6) + l];
        s16x8 b2 = Bp[((size_t)((kt+3)*NCT + ct0 + 2) << 6) + l];
        s16x8 b3 = Bp[((size_t)((kt+3)*NCT + ct0 + 3) << 6) + l];
        acc[0][0] = __builtin_amdgcn_mfma_f32_16x16x32_bf16(a0, b0, acc[0][0], 0, 0, 0);
        acc[0][1] = __builtin_amdgcn_mfma_f32_16x16x32_bf16(a0, b1, acc[0][1], 0, 0, 0);
        acc[0][2] = __builtin_amdgcn_mfma_f32_16x16x32_bf16(a0, b2, acc[0][2], 0, 0, 0);
        acc[0][3] = __builtin_amdgcn_mfma_f32_16x16x32_bf16(a0, b3, acc[0][3], 0, 0, 0);
        acc[1][0] = __builtin_amdgcn_mfma_f32_16x16x32_bf16(a1, b0, acc[1][0], 0, 0, 0);
        acc[1][1] = __builtin_amdgcn_mfma_f32_16x16x32_bf16(a1, b1, acc[1][1], 0, 0, 0);
        acc[1][2] = __builtin_amdgcn_mfma_f32_16x16x32_bf16(a1, b2, acc[1][2], 0, 0, 0);
        acc[1][3] = __builtin_amdgcn_mfma_f32_16x16x32_bf16(a1, b3, acc[1][3], 0, 0, 0);
    }

    // ---- epilogue ----
    const float pt = (PHASE == 1) ? probs[t] : 0.f;
    #pragma unroll
    for (int af = 0; af < 2; ++af){
        #pragma unroll
        for (int bf = 0; bf < 4; ++bf){
            const int c_full = colbase + bf*16 + lr;
            const float bias = bp[c_full];
            #pragma unroll
            for (int r = 0; r < 4; ++r){
                const int m = row0 + af*16 + lk*4 + r;
                if (m >= M_TOT) continue;
                float v = acc[af][bf][r] + bias;
                if (PHASE == 0){
                    float s = 1.f/(1.f + __expf(-v));
                    if (c_full < 256){
                        Zb[(size_t)m*C_ + c_full] = s;
                    } else {
                        int c2 = c_full - 256;
                        float hr = H[(size_t)m*C_ + c2] * s;
                        HRb[(size_t)m*C_ + c2] = __float2bfloat16(hr);
                    }
                } else {
                    int c2 = c_full - 512;
                    float ht = 1.f - 2.f/(__expf(2.f*v) + 1.f);
                    float z = Zb[(size_t)m*C_ + c2];
                    float h = H[(size_t)m*C_ + c2];
                    float hn = z*h + (1.f - z)*ht;
                    H[(size_t)m*C_ + c2] = hn;
                    Hb[(size_t)m*C_ + c2] = __float2bfloat16(hn);
                    Hacc[(size_t)m*C_ + c2] += pt*hn;
                }
            }
        }
    }
}

// ---------------- final MLP ----------------
__global__ __launch_bounds__(256) void mlp_kernel(const float* __restrict__ Hacc, const int* __restrict__ fids,
                           const float* __restrict__ M1, const float* __restrict__ M1b,
                           const float* __restrict__ M2, const float* __restrict__ M2b,
                           const float* __restrict__ M3, const float* __restrict__ M3b,
                           float* __restrict__ out){
    const int b = blockIdx.x;
    const int tid = threadIdx.x;
    __shared__ float sh[C_];
    __shared__ float s1[64];
    __shared__ float s2[32];
    const int f = fids[b];
    sh[tid] = Hacc[((size_t)(b*N_ + f))*C_ + tid];
    __syncthreads();
    if (tid < 64){
        float a = M1b[tid];
        for (int k = 0; k < C_; ++k) a += sh[k]*M1[k*64 + tid];
        s1[tid] = (a > 0.f) ? a : 0.01f*a;
    }
    __syncthreads();
    if (tid < 32){
        float a = M2b[tid];
        for (int k = 0; k < 64; ++k) a += s1[k]*M2[k*32 + tid];
        s2[tid] = (a > 0.f) ? a : 0.01f*a;
    }
    __syncthreads();
    if (tid < 5){
        float a = M3b[tid];
        for (int k = 0; k < 32; ++k) a += s2[k]*M3[k*5 + tid];
        out[b*5 + tid] = 4.f/(1.f + expf(-a)) + 1.f;
    }
}

extern "C" void kernel_launch(void* const* d_in, const int* in_sizes, int n_in,
                              void* d_out, int out_size, void* d_ws, size_t ws_size,
                              hipStream_t stream) {
    const float* x   = (const float*)d_in[0];
    const int*   ei  = (const int*)d_in[1];
    const int*   fid = (const int*)d_in[2];
    const float* att = (const float*)d_in[3];
    const float* Wz  = (const float*)d_in[4];  const float* bz  = (const float*)d_in[5];
    const float* Wr  = (const float*)d_in[6];  const float* br  = (const float*)d_in[7];
    const float* Wh  = (const float*)d_in[8];  const float* bh  = (const float*)d_in[9];
    const float* Lz  = (const float*)d_in[10]; const float* Lzb = (const float*)d_in[11];
    const float* Lr  = (const float*)d_in[12]; const float* Lrb = (const float*)d_in[13];
    const float* Lh  = (const float*)d_in[14]; const float* Lhb = (const float*)d_in[15];
    const float* M1  = (const float*)d_in[16]; const float* M1b = (const float*)d_in[17];
    const float* M2  = (const float*)d_in[18]; const float* M2b = (const float*)d_in[19];
    const float* M3  = (const float*)d_in[20]; const float* M3b = (const float*)d_in[21];
    float* out = (float*)d_out;

    char* w = (char*)d_ws;
    auto alloc = [&](size_t bytes)->void*{ void* p = (void*)w; w += ((bytes + 255)/256)*256; return p; };
    int*   cnt     = (int*)  alloc((size_t)N_*4);
    int*   rowptr  = (int*)  alloc((size_t)(N_+1)*4);
    int*   pos     = (int*)  alloc((size_t)N_*4);
    float* dis     = (float*)alloc((size_t)N_*4);
    float* selfw   = (float*)alloc((size_t)N_*4);
    int*   csr_src = (int*)  alloc((size_t)E_*4);
    float* csr_w   = (float*)alloc((size_t)E_*4);
    float* probs   = (float*)alloc((size_t)T_*4);
    float* Wp      = (float*)alloc((size_t)F_*768*4);
    float* bp      = (float*)alloc((size_t)768*4);
    __hip_bfloat16* Bp  = (__hip_bfloat16*)alloc((size_t)NKT*NCT*64*8*2);
    __hip_bfloat16* Axp = (__hip_bfloat16*)alloc((size_t)M_PAD*KP_*2);
    float*          H   = (float*)alloc((size_t)M_PAD*C_*4);
    __hip_bfloat16* Hb  = (__hip_bfloat16*)alloc((size_t)M_PAD*C_*2);
    __hip_bfloat16* HRb = (__hip_bfloat16*)alloc((size_t)M_PAD*C_*2);
    float*          Zb  = (float*)alloc((size_t)M_PAD*C_*4);
    float*          Hacc= (float*)alloc((size_t)M_TOT*C_*4);

    init_kernel<<<2048, 256, 0, stream>>>(cnt, H, Hacc, (unsigned*)Hb, (unsigned*)Axp, (unsigned*)HRb);
    count_kernel<<<(E_ + 255)/256, 256, 0, stream>>>(ei, cnt);
    dis_kernel<<<(N_ + 255)/256, 256, 0, stream>>>(cnt, dis, selfw);
    scan_kernel<<<1, 256, 0, stream>>>(cnt, rowptr, pos);
    scatter_kernel<<<(E_ + 255)/256, 256, 0, stream>>>(ei, dis, pos, csr_src, csr_w);
    softmax_kernel<<<1, 64, 0, stream>>>(att, probs);
    foldw_kernel<<<3*F_, 256, 0, stream>>>(Wz, Wr, Wh, Lz, Lr, Lh, Wp);
    foldb_kernel<<<3, 256, 0, stream>>>(bz, br, bh, Lz, Lr, Lh, Lzb, Lrb, Lhb, bp);
    pack_kernel<<<NKT*NCT, 256, 0, stream>>>(Wp, Lz, Lr, Lh, Bp);

    const dim3 grid0((M_TOT + 63)/64, 4);   // 512 cols, 128/block
    const dim3 grid1((M_TOT + 63)/64, 2);   // 256 cols

    for (int t = 0; t < T_; ++t){
        spmm_kernel<<<N_, 256, 0, stream>>>(x, rowptr, csr_src, csr_w, selfw, Axp, t);
        gemm_mfma<0><<<grid0, 256, 0, stream>>>((const s16x8*)Axp, (const s16x8*)Hb, (const s16x8*)Bp,
                                                bp, H, Zb, HRb, nullptr, nullptr, probs, t);
        gemm_mfma<1><<<grid1, 256, 0, stream>>>((const s16x8*)Axp, (const s16x8*)HRb, (const s16x8*)Bp,
                                                bp, H, Zb, nullptr, Hb, Hacc, probs, t);
    }
    mlp_kernel<<<B_, 256, 0, stream>>>(Hacc, fid, M1, M1b, M2, M2b, M3, M3b, out);
}

// Round 3
// 3811.546 us; speedup vs baseline: 2.8241x; 1.2357x over previous
//
#include <hip/hip_runtime.h>
#include <hip/hip_bf16.h>
#include <cmath>

#define B_ 4
#define T_ 40
#define N_ 5000
#define F_ 90
#define C_ 256
#define E_ 160000
#define M_TOT (B_*N_)   // 20000
#define M_PAD 20032     // 313*64
#define KP_ 96          // padded F (multiple of 32)
#define NKT 11          // (96+256)/32
#define NCT 48          // 768/16
#define NBLK 313        // M_PAD/64

typedef __attribute__((ext_vector_type(8))) short s16x8;
typedef __attribute__((ext_vector_type(4))) float f32x4;

__device__ inline unsigned short f2bf(float v){
    union { __hip_bfloat16 b; unsigned short u; } cv;
    cv.b = __float2bfloat16(v);
    return cv.u;
}

// ---------------- init: cnt zeros + Axp_all padded-row zeros ----------------
__global__ void init_kernel(int* __restrict__ cnt, unsigned* __restrict__ AxpU){
    const int i = blockIdx.x*blockDim.x + threadIdx.x;
    const int stride = gridDim.x*blockDim.x;
    for (int j = i; j < N_; j += stride) cnt[j] = 0;
    const int padw = (M_PAD - M_TOT)*KP_/2;        // u32 words per t
    const int tot = T_*padw;
    for (int j = i; j < tot; j += stride){
        int t = j / padw, o = j - t*padw;
        AxpU[(size_t)t*(M_PAD*KP_/2) + (M_TOT*KP_/2) + o] = 0u;
    }
}

// ---------------- degree count ----------------
__global__ void count_kernel(const int* __restrict__ ei, int* __restrict__ cnt){
    int e = blockIdx.x*blockDim.x + threadIdx.x;
    if (e < E_) atomicAdd(&cnt[ei[E_ + e]], 1);
}

// ---------------- dis = deg^-0.5, selfw = dis^2 ----------------
__global__ void dis_kernel(const int* __restrict__ cnt, float* __restrict__ dis, float* __restrict__ selfw){
    int n = blockIdx.x*blockDim.x + threadIdx.x;
    if (n < N_){
        float d = (float)cnt[n] + 1.0f;
        float r = 1.0f / sqrtf(d);
        dis[n] = r;
        selfw[n] = r*r;
    }
}

// ---------------- exclusive scan over cnt -> rowptr, pos ----------------
__global__ __launch_bounds__(256) void scan_kernel(const int* __restrict__ cnt, int* __restrict__ rowptr, int* __restrict__ pos){
    const int tid = threadIdx.x;
    const int base = tid*20;
    int v[20]; int s = 0;
    #pragma unroll
    for (int j = 0; j < 20; ++j){
        int idx = base + j;
        int c = (idx < N_) ? cnt[idx] : 0;
        v[j] = s; s += c;
    }
    __shared__ int sh[256];
    sh[tid] = s; __syncthreads();
    for (int off = 1; off < 256; off <<= 1){
        int x = (tid >= off) ? sh[tid-off] : 0;
        __syncthreads();
        sh[tid] += x;
        __syncthreads();
    }
    int excl = sh[tid] - s;
    #pragma unroll
    for (int j = 0; j < 20; ++j){
        int idx = base + j;
        if (idx < N_){ int val = excl + v[j]; rowptr[idx] = val; pos[idx] = val; }
    }
    if (tid == 255) rowptr[N_] = sh[255];
}

// ---------------- CSR scatter ----------------
__global__ void scatter_kernel(const int* __restrict__ ei, const float* __restrict__ dis,
                               int* __restrict__ pos, int* __restrict__ csr_src, float* __restrict__ csr_w){
    int e = blockIdx.x*blockDim.x + threadIdx.x;
    if (e < E_){
        int r = ei[e];
        int c = ei[E_ + e];
        int p = atomicAdd(&pos[c], 1);
        csr_src[p] = r;
        csr_w[p]   = dis[r]*dis[c];
    }
}

// ---------------- softmax over attention (T=40) ----------------
__global__ void softmax_kernel(const float* __restrict__ att, float* __restrict__ probs){
    int t = threadIdx.x;
    float v = (t < T_) ? att[t] : -3.4e38f;
    float m = v;
    for (int o = 32; o > 0; o >>= 1) m = fmaxf(m, __shfl_xor(m, o));
    float e = (t < T_) ? expf(v - m) : 0.f;
    float s = e;
    for (int o = 32; o > 0; o >>= 1) s += __shfl_xor(s, o);
    if (t < T_) probs[t] = e / s;
}

// ---------------- fold weights: Wp[f][g*256+c] = sum_k Wg[f][k]*Lg[k][c] ----------------
__global__ __launch_bounds__(256) void foldw_kernel(const float* __restrict__ Wz, const float* __restrict__ Wr, const float* __restrict__ Wh,
                             const float* __restrict__ Lz, const float* __restrict__ Lr, const float* __restrict__ Lh,
                             float* __restrict__ Wp){
    int g = blockIdx.x / F_;
    int f = blockIdx.x % F_;
    int c = threadIdx.x;
    const float* W = (g == 0) ? Wz : (g == 1) ? Wr : Wh;
    const float* L = (g == 0) ? Lz : (g == 1) ? Lr : Lh;
    float acc = 0.f;
    for (int k = 0; k < C_; ++k) acc += W[f*C_ + k] * L[k*C_ + c];
    Wp[f*768 + g*256 + c] = acc;
}

__global__ __launch_bounds__(256) void foldb_kernel(const float* __restrict__ bz, const float* __restrict__ br, const float* __restrict__ bh,
                             const float* __restrict__ Lz, const float* __restrict__ Lr, const float* __restrict__ Lh,
                             const float* __restrict__ Lzb, const float* __restrict__ Lrb, const float* __restrict__ Lhb,
                             float* __restrict__ bp){
    int g = blockIdx.x;
    int c = threadIdx.x;
    const float* b = (g == 0) ? bz : (g == 1) ? br : bh;
    const float* L = (g == 0) ? Lz : (g == 1) ? Lr : Lh;
    const float* lb = (g == 0) ? Lzb : (g == 1) ? Lrb : Lhb;
    float acc = lb[c];
    for (int k = 0; k < C_; ++k) acc += b[k] * L[k*C_ + c];
    bp[g*256 + c] = acc;
}

// ---------------- pack folded weight [352][768] into MFMA B-fragment order ----------------
__global__ __launch_bounds__(256) void pack_kernel(const float* __restrict__ Wp,
                             const float* __restrict__ Lz, const float* __restrict__ Lr, const float* __restrict__ Lh,
                             __hip_bfloat16* __restrict__ Bp){
    const int kt = blockIdx.x / NCT;
    const int ct = blockIdx.x % NCT;
    const int tid = threadIdx.x;
    const int l = tid & 63;
    const int jp = tid >> 6;
    const int c = ct*16 + (l & 15);
    #pragma unroll
    for (int jj = 0; jj < 2; ++jj){
        const int j = jp*2 + jj;
        const int k = kt*32 + (l >> 4)*8 + j;
        float v;
        if (k < F_) v = Wp[k*768 + c];
        else if (k < KP_) v = 0.f;
        else {
            int kk = k - KP_;
            int g = c >> 8, c2 = c & 255;
            const float* L = (g == 0) ? Lz : (g == 1) ? Lr : Lh;
            v = L[(256 + kk)*C_ + c2];
        }
        Bp[((size_t)(kt*NCT + ct)*64 + l)*8 + j] = __float2bfloat16(v);
    }
}

// ---------------- SpMM for ALL timesteps: Axp[t][b*N+n][f] ----------------
__global__ __launch_bounds__(256) void spmm_all_kernel(const float* __restrict__ X, const int* __restrict__ rowptr,
                            const int* __restrict__ csr_src, const float* __restrict__ csr_w,
                            const float* __restrict__ selfw, __hip_bfloat16* __restrict__ AxpAll){
    const int n = blockIdx.x;
    const int t = blockIdx.y;
    const int tid = threadIdx.x;
    __hip_bfloat16* Axp = AxpAll + (size_t)t*M_PAD*KP_;
    __shared__ int   s_src[256];
    __shared__ float s_w[256];
    const int beg = rowptr[n], end = rowptr[n+1];
    const int i0 = tid, i1 = tid + 256;
    const int b0 = i0 / F_, f0 = i0 - b0*F_;
    const int b1 = i1 / F_, f1 = i1 - b1*F_;
    const bool has1 = (i1 < B_*F_);
    const float sw = selfw[n];
    float acc0 = sw * X[((size_t)(b0*T_ + t)*N_ + n)*F_ + f0];
    float acc1 = has1 ? sw * X[((size_t)(b1*T_ + t)*N_ + n)*F_ + f1] : 0.f;
    for (int base = beg; base < end; base += 256){
        int cc = min(256, end - base);
        __syncthreads();
        if (tid < cc){ s_src[tid] = csr_src[base + tid]; s_w[tid] = csr_w[base + tid]; }
        __syncthreads();
        for (int j = 0; j < cc; ++j){
            int src = s_src[j]; float wv = s_w[j];
            acc0 += wv * X[((size_t)(b0*T_ + t)*N_ + src)*F_ + f0];
            if (has1) acc1 += wv * X[((size_t)(b1*T_ + t)*N_ + src)*F_ + f1];
        }
    }
    Axp[(size_t)(b0*N_ + n)*KP_ + f0] = __float2bfloat16(acc0);
    if (has1) Axp[(size_t)(b1*N_ + n)*KP_ + f1] = __float2bfloat16(acc1);
    if (tid < B_*(KP_ - F_)){
        int b = tid / (KP_ - F_), f = F_ + tid % (KP_ - F_);
        Axp[(size_t)(b*N_ + n)*KP_ + f] = __float2bfloat16(0.f);
    }
}

// ---------------- fused 40-step GRU: each block owns 64 rows; H,z,Hacc in regs ----------------
// Per step: zr-chunk (K=96 Axp + K=256 Hb_lds) -> z regs + HR_lds;
//           h-chunk  (K=96 Axp + K=256 HR_lds) -> H update, Hacc accum, Hb_lds.
__global__ __launch_bounds__(512, 2) void gru_fused(
    const s16x8* __restrict__ Axp,   // [T][M_PAD][12]
    const s16x8* __restrict__ Bp,    // [(kt*NCT+ct)*64 + lane]
    const float* __restrict__ bp,    // [768]
    const float* __restrict__ probs, // [T]
    float* __restrict__ Hacc)        // [M_TOT][C]
{
    __shared__ __align__(16) unsigned short HbL[64*256];  // [m][k] bf16, XOR-swizzled
    __shared__ __align__(16) unsigned short HRL[64*256];
    const int tid = threadIdx.x;
    const int l = tid & 63, w = tid >> 6;      // wave 0..7 -> col group w*32
    const int lr = l & 15, lk = l >> 4;
    const int row0 = blockIdx.x * 64;

    // zero Hb (initial state)
    {
        unsigned* p = (unsigned*)HbL;
        for (int i = tid; i < 64*128; i += 512) p[i] = 0u;
    }

    f32x4 zf[4][2], Hreg[4][2], Ha[4][2];
    #pragma unroll
    for (int a = 0; a < 4; ++a)
        #pragma unroll
        for (int c = 0; c < 2; ++c){ zf[a][c] = {}; Hreg[a][c] = {}; Ha[a][c] = {}; }

    float bz_[2], br_[2], bh_[2];
    #pragma unroll
    for (int cf = 0; cf < 2; ++cf){
        const int c = w*32 + cf*16 + lr;
        bz_[cf] = bp[c]; br_[cf] = bp[256 + c]; bh_[cf] = bp[512 + c];
    }

    // LDS A-frag read addressing: row m = af*16+lr, byte = m*512 + kb + lk*16, then ^((m&7)<<4)
    int ardb[4], asw[4];
    #pragma unroll
    for (int af = 0; af < 4; ++af){
        const int m = af*16 + lr;
        ardb[af] = m*512 + lk*16;
        asw[af]  = (m & 7) << 4;
    }

    for (int t = 0; t < T_; ++t){
        __syncthreads();                        // Hb ready (init or prev h-epilogue)
        const s16x8* At = Axp + (size_t)t * (M_PAD * 12);

        // ---------- zr chunk ----------
        f32x4 az[4][2] = {}, ar[4][2] = {};
        #pragma unroll
        for (int kt = 0; kt < NKT; ++kt){
            s16x8 a[4];
            if (kt < 3){
                #pragma unroll
                for (int af = 0; af < 4; ++af)
                    a[af] = At[(size_t)(row0 + af*16 + lr)*12 + kt*4 + lk];
            } else {
                const int kb = (kt - 3)*64;
                #pragma unroll
                for (int af = 0; af < 4; ++af)
                    a[af] = *(const s16x8*)((const char*)HbL + ((ardb[af] + kb) ^ asw[af]));
            }
            const s16x8* Bk = Bp + ((size_t)(kt*NCT) << 6);
            const s16x8 bz0 = Bk[((size_t)(2*w + 0) << 6) + l];
            const s16x8 bz1 = Bk[((size_t)(2*w + 1) << 6) + l];
            const s16x8 br0 = Bk[((size_t)(16 + 2*w) << 6) + l];
            const s16x8 br1 = Bk[((size_t)(17 + 2*w) << 6) + l];
            #pragma unroll
            for (int af = 0; af < 4; ++af){
                az[af][0] = __builtin_amdgcn_mfma_f32_16x16x32_bf16(a[af], bz0, az[af][0], 0, 0, 0);
                az[af][1] = __builtin_amdgcn_mfma_f32_16x16x32_bf16(a[af], bz1, az[af][1], 0, 0, 0);
                ar[af][0] = __builtin_amdgcn_mfma_f32_16x16x32_bf16(a[af], br0, ar[af][0], 0, 0, 0);
                ar[af][1] = __builtin_amdgcn_mfma_f32_16x16x32_bf16(a[af], br1, ar[af][1], 0, 0, 0);
            }
        }
        // zr epilogue: z regs, HR -> LDS
        #pragma unroll
        for (int af = 0; af < 4; ++af){
            #pragma unroll
            for (int cf = 0; cf < 2; ++cf){
                const int c2 = w*32 + cf*16 + lr;
                #pragma unroll
                for (int r = 0; r < 4; ++r){
                    const float zv = 1.f/(1.f + __expf(-(az[af][cf][r] + bz_[cf])));
                    const float sv = 1.f/(1.f + __expf(-(ar[af][cf][r] + br_[cf])));
                    zf[af][cf][r] = zv;
                    const float hr = Hreg[af][cf][r] * sv;
                    const int m2 = af*16 + lk*4 + r;
                    const int wb = (m2*512 + c2*2) ^ ((m2 & 7) << 4);
                    *(unsigned short*)((char*)HRL + wb) = f2bf(hr);
                }
            }
        }
        __syncthreads();                        // HR ready; Hb reads done

        // ---------- h chunk ----------
        f32x4 ah[4][2] = {};
        #pragma unroll
        for (int kt = 0; kt < NKT; ++kt){
            s16x8 a[4];
            if (kt < 3){
                #pragma unroll
                for (int af = 0; af < 4; ++af)
                    a[af] = At[(size_t)(row0 + af*16 + lr)*12 + kt*4 + lk];
            } else {
                const int kb = (kt - 3)*64;
                #pragma unroll
                for (int af = 0; af < 4; ++af)
                    a[af] = *(const s16x8*)((const char*)HRL + ((ardb[af] + kb) ^ asw[af]));
            }
            const s16x8* Bk = Bp + ((size_t)(kt*NCT) << 6);
            const s16x8 bh0 = Bk[((size_t)(32 + 2*w) << 6) + l];
            const s16x8 bh1 = Bk[((size_t)(33 + 2*w) << 6) + l];
            #pragma unroll
            for (int af = 0; af < 4; ++af){
                ah[af][0] = __builtin_amdgcn_mfma_f32_16x16x32_bf16(a[af], bh0, ah[af][0], 0, 0, 0);
                ah[af][1] = __builtin_amdgcn_mfma_f32_16x16x32_bf16(a[af], bh1, ah[af][1], 0, 0, 0);
            }
        }
        // h epilogue: H update (regs), Hacc accum (regs), Hb -> LDS
        const float pt = probs[t];
        #pragma unroll
        for (int af = 0; af < 4; ++af){
            #pragma unroll
            for (int cf = 0; cf < 2; ++cf){
                const int c2 = w*32 + cf*16 + lr;
                #pragma unroll
                for (int r = 0; r < 4; ++r){
                    const float v = ah[af][cf][r] + bh_[cf];
                    const float ht = 1.f - 2.f/(__expf(2.f*v) + 1.f);
                    const float zv = zf[af][cf][r];
                    const float hn = zv*Hreg[af][cf][r] + (1.f - zv)*ht;
                    Hreg[af][cf][r] = hn;
                    Ha[af][cf][r] += pt*hn;
                    const int m2 = af*16 + lk*4 + r;
                    const int wb = (m2*512 + c2*2) ^ ((m2 & 7) << 4);
                    *(unsigned short*)((char*)HbL + wb) = f2bf(hn);
                }
            }
        }
    }

    // write Hacc
    #pragma unroll
    for (int af = 0; af < 4; ++af){
        #pragma unroll
        for (int cf = 0; cf < 2; ++cf){
            #pragma unroll
            for (int r = 0; r < 4; ++r){
                const int m = row0 + af*16 + lk*4 + r;
                if (m < M_TOT)
                    Hacc[(size_t)m*C_ + w*32 + cf*16 + lr] = Ha[af][cf][r];
            }
        }
    }
}

// ---------------- final MLP ----------------
__global__ __launch_bounds__(256) void mlp_kernel(const float* __restrict__ Hacc, const int* __restrict__ fids,
                           const float* __restrict__ M1, const float* __restrict__ M1b,
                           const float* __restrict__ M2, const float* __restrict__ M2b,
                           const float* __restrict__ M3, const float* __restrict__ M3b,
                           float* __restrict__ out){
    const int b = blockIdx.x;
    const int tid = threadIdx.x;
    __shared__ float sh[C_];
    __shared__ float s1[64];
    __shared__ float s2[32];
    const int f = fids[b];
    sh[tid] = Hacc[((size_t)(b*N_ + f))*C_ + tid];
    __syncthreads();
    if (tid < 64){
        float a = M1b[tid];
        for (int k = 0; k < C_; ++k) a += sh[k]*M1[k*64 + tid];
        s1[tid] = (a > 0.f) ? a : 0.01f*a;
    }
    __syncthreads();
    if (tid < 32){
        float a = M2b[tid];
        for (int k = 0; k < 64; ++k) a += s1[k]*M2[k*32 + tid];
        s2[tid] = (a > 0.f) ? a : 0.01f*a;
    }
    __syncthreads();
    if (tid < 5){
        float a = M3b[tid];
        for (int k = 0; k < 32; ++k) a += s2[k]*M3[k*5 + tid];
        out[b*5 + tid] = 4.f/(1.f + expf(-a)) + 1.f;
    }
}

extern "C" void kernel_launch(void* const* d_in, const int* in_sizes, int n_in,
                              void* d_out, int out_size, void* d_ws, size_t ws_size,
                              hipStream_t stream) {
    const float* x   = (const float*)d_in[0];
    const int*   ei  = (const int*)d_in[1];
    const int*   fid = (const int*)d_in[2];
    const float* att = (const float*)d_in[3];
    const float* Wz  = (const float*)d_in[4];  const float* bz  = (const float*)d_in[5];
    const float* Wr  = (const float*)d_in[6];  const float* br  = (const float*)d_in[7];
    const float* Wh  = (const float*)d_in[8];  const float* bh  = (const float*)d_in[9];
    const float* Lz  = (const float*)d_in[10]; const float* Lzb = (const float*)d_in[11];
    const float* Lr  = (const float*)d_in[12]; const float* Lrb = (const float*)d_in[13];
    const float* Lh  = (const float*)d_in[14]; const float* Lhb = (const float*)d_in[15];
    const float* M1  = (const float*)d_in[16]; const float* M1b = (const float*)d_in[17];
    const float* M2  = (const float*)d_in[18]; const float* M2b = (const float*)d_in[19];
    const float* M3  = (const float*)d_in[20]; const float* M3b = (const float*)d_in[21];
    float* out = (float*)d_out;

    char* w = (char*)d_ws;
    auto alloc = [&](size_t bytes)->void*{ void* p = (void*)w; w += ((bytes + 255)/256)*256; return p; };
    int*   cnt     = (int*)  alloc((size_t)N_*4);
    int*   rowptr  = (int*)  alloc((size_t)(N_+1)*4);
    int*   pos     = (int*)  alloc((size_t)N_*4);
    float* dis     = (float*)alloc((size_t)N_*4);
    float* selfw   = (float*)alloc((size_t)N_*4);
    int*   csr_src = (int*)  alloc((size_t)E_*4);
    float* csr_w   = (float*)alloc((size_t)E_*4);
    float* probs   = (float*)alloc((size_t)T_*4);
    float* Wp      = (float*)alloc((size_t)F_*768*4);
    float* bp      = (float*)alloc((size_t)768*4);
    __hip_bfloat16* Bp     = (__hip_bfloat16*)alloc((size_t)NKT*NCT*64*8*2);
    __hip_bfloat16* AxpAll = (__hip_bfloat16*)alloc((size_t)T_*M_PAD*KP_*2);   // ~154 MB
    float*          Hacc   = (float*)alloc((size_t)M_TOT*C_*4);

    init_kernel<<<256, 256, 0, stream>>>(cnt, (unsigned*)AxpAll);
    count_kernel<<<(E_ + 255)/256, 256, 0, stream>>>(ei, cnt);
    dis_kernel<<<(N_ + 255)/256, 256, 0, stream>>>(cnt, dis, selfw);
    scan_kernel<<<1, 256, 0, stream>>>(cnt, rowptr, pos);
    scatter_kernel<<<(E_ + 255)/256, 256, 0, stream>>>(ei, dis, pos, csr_src, csr_w);
    softmax_kernel<<<1, 64, 0, stream>>>(att, probs);
    foldw_kernel<<<3*F_, 256, 0, stream>>>(Wz, Wr, Wh, Lz, Lr, Lh, Wp);
    foldb_kernel<<<3, 256, 0, stream>>>(bz, br, bh, Lz, Lr, Lh, Lzb, Lrb, Lhb, bp);
    pack_kernel<<<NKT*NCT, 256, 0, stream>>>(Wp, Lz, Lr, Lh, Bp);

    spmm_all_kernel<<<dim3(N_, T_), 256, 0, stream>>>(x, rowptr, csr_src, csr_w, selfw, AxpAll);
    gru_fused<<<NBLK, 512, 0, stream>>>((const s16x8*)AxpAll, (const s16x8*)Bp, bp, probs, Hacc);
    mlp_kernel<<<B_, 256, 0, stream>>>(Hacc, fid, M1, M1b, M2, M2b, M3, M3b, out);
}